// Round 11
// baseline (61.226 us; speedup 1.0000x reference)
//
#include <hip/hip_runtime.h>
#include <hip/hip_bf16.h>

// BinaryReflectanceGate: pointwise MLP (4->16->16, relu) -> segment max over
// sorted batch ids [B=64] -> 2-logit gate + gumbel softmax -> scale reflectance.
//
// Round-11: r10 kernel body (proven correct, straight-line fast path) with
// LATENCY-HIDING GEOMETRY: SITERS=1, NBLK=4096 -> 8 blocks/CU resident
// (VGPR<=64 via __launch_bounds__(256,8), LDS 1KB) = up to 32 waves/CU of
// independent load->MLP chains. r10's 1024-block grid capped occupancy at
// 28% and left the kernel latency-bound (VALUBusy 17%, HBM 7%).
//
// MFMA layout facts (HW-verified r4, absmax 0.0039):
//   C/D: col=lane&15, row=(lane>>4)*4+reg. Lane l owns points 4l..4l+3 of its
//   wave's 256-pt chunk (pos floats 12l..12l+11 = 3 aligned float4s + refl
//   float4). In MFMA (j,t), lanes with g==t feed their j-th point; column c's
//   point id = sb + 4*(16t+c) + j (closed form, used for straddle select).

#define N_PTS 4194304
#define NB 64
#define NH 16
#define WPB 4                       // waves per block
#define PTW 256                     // points per wave (one chunk)
#define PPB (WPB * PTW)             // 1024 points per block
#define NBLK (N_PTS / PPB)          // 4096 blocks
#define NENT (NBLK * 2)             // 8192 partial entries

typedef __attribute__((ext_vector_type(8))) short bf16x8;
typedef __attribute__((ext_vector_type(4))) float f32x4;
union U8 { bf16x8 v; unsigned u[4]; unsigned short s[8]; };

struct Rec { int idA, idB, bpos; };

__device__ __forceinline__ unsigned pk2(float a, float b) {
    float2 t; t.x = a; t.y = b;
    __hip_bfloat162 r = __float22bfloat162_rn(t);
    unsigned u;
    __builtin_memcpy(&u, &r, sizeof(u));
    return u;
}
__device__ __forceinline__ unsigned short f2bf(float x) {   // RNE, setup only
    unsigned u = __float_as_uint(x);
    u = u + 0x7fffu + ((u >> 16) & 1u);
    return (unsigned short)(u >> 16);
}

// One 256-pt chunk: lane's 4 points through both layers, phase-split for ILP.
template<bool SLOW>
__device__ __forceinline__ void do_chunk(
    const float4& q0, const float4& q1, const float4& q2, const float4& rr,
    int sb, int g, int col, int bposw,
    const U8& A1, const U8& A2, const f32x4& c1, const f32x4& c2,
    f32x4& accA, f32x4& accB)
{
    const float f[4][4] = {{q0.x, q0.y, q0.z, rr.x},
                           {q0.w, q1.x, q1.y, rr.y},
                           {q1.z, q1.w, q2.x, rr.z},
                           {q2.y, q2.z, q2.w, rr.w}};
#pragma unroll
    for (int j = 0; j < 4; ++j) {
        const unsigned F01 = pk2(f[j][0], f[j][1]);
        const unsigned F23 = pk2(f[j][2], f[j][3]);
        f32x4 d[4], h[4];                 // static-indexed (fully unrolled)
#pragma unroll
        for (int t = 0; t < 4; ++t) {     // phase 1: 4 independent MFMA1
            const bool mine = (g == t);
            U8 B;
            B.u[0] = mine ? F01 : 0u;
            B.u[1] = mine ? F23 : 0u;
            B.u[2] = 0u; B.u[3] = 0u;
            d[t] = __builtin_amdgcn_mfma_f32_16x16x32_bf16(A1.v, B.v, c1, 0, 0, 0);
        }
#pragma unroll
        for (int t = 0; t < 4; ++t) {     // phase 2+3: pack, 4 MFMA2
            U8 P;
            P.u[0] = pk2(fmaxf(d[t][0], 0.f), fmaxf(d[t][1], 0.f));
            P.u[1] = pk2(fmaxf(d[t][2], 0.f), fmaxf(d[t][3], 0.f));
            P.u[2] = 0u; P.u[3] = 0u;
            h[t] = __builtin_amdgcn_mfma_f32_16x16x32_bf16(A2.v, P.v, c2, 0, 0, 0);
        }
#pragma unroll
        for (int t = 0; t < 4; ++t) {     // phase 4: accumulate
            if (!SLOW) {
#pragma unroll
                for (int r = 0; r < 4; ++r) accA[r] = fmaxf(accA[r], h[t][r]);
            } else {
                const bool m = (sb + 4 * (16 * t + col) + j) < bposw;
#pragma unroll
                for (int r = 0; r < 4; ++r) {
                    accA[r] = fmaxf(accA[r], m ? h[t][r] : 0.f);
                    accB[r] = fmaxf(accB[r], m ? 0.f : h[t][r]);
                }
            }
        }
    }
}

// ---------------- A: MLP + segment-max partials + records ----------------
__global__ __launch_bounds__(256, 8) void mlp_segmax_kernel(
    const float* __restrict__ pos,    // [N,3]
    const float* __restrict__ refl,   // [N]
    const int*   __restrict__ batch,  // [N] sorted
    const float* __restrict__ W1, const float* __restrict__ b1,
    const float* __restrict__ W2, const float* __restrict__ b2,
    float* __restrict__ pv,           // [NENT,16]
    int*   __restrict__ pid,          // [NENT]
    Rec*   __restrict__ recs)         // [NBLK]
{
    __shared__ float lv[WPB][2][NH];
    __shared__ int   li[WPB][2];
    __shared__ int   lbp[WPB];

    const int lane = threadIdx.x & 63;
    const int wid  = threadIdx.x >> 6;
    const int col  = lane & 15;
    const int g    = lane >> 4;
    const int wb   = (blockIdx.x * WPB + wid) * PTW;

    // weight / bias fragments (L1-cached one-time loads)
    U8 A1, A2;
#pragma unroll
    for (int e = 0; e < 4; ++e) {
        A1.s[e]     = f2bf(W1[e * NH + col]);
        A1.s[e + 4] = 0;
        A2.s[e]     = f2bf(W2[(4 * g + e) * NH + col]);
        A2.s[e + 4] = 0;
    }
    f32x4 c1, c2;
#pragma unroll
    for (int r = 0; r < 4; ++r) { c1[r] = b1[4 * g + r]; c2[r] = b2[4 * g + r]; }

    const int idA = batch[wb];
    const int idB = batch[wb + PTW - 1];
    const bool isSlow = (idA != idB);      // wave-uniform

    f32x4 accA = {0.f, 0.f, 0.f, 0.f};
    f32x4 accB = {0.f, 0.f, 0.f, 0.f};

    const float4* gp = (const float4*)(pos + (size_t)wb * 3);
    const float4* gr = (const float4*)(refl + wb);

    const float4 q0 = gp[3 * lane + 0];
    const float4 q1 = gp[3 * lane + 1];
    const float4 q2 = gp[3 * lane + 2];
    const float4 rr = gr[lane];

    if (!isSlow) {
        // ---- fast path: straight-line ----
        do_chunk<false>(q0, q1, q2, rr, wb, g, col, 0,
                        A1, A2, c1, c2, accA, accB);
    } else {
        // ---- slow path (~63 waves): boundary scan, then select-accumulate
        int bposw = 0x7fffffff;
        for (int it = 0; it < PTW / 64; ++it) {
            const int idx = wb + it * 64 + lane;
            const unsigned long long mk = __ballot(batch[idx] != idA);
            if (mk) bposw = min(bposw, wb + it * 64 + (__ffsll((long long)mk) - 1));
        }
        do_chunk<true>(q0, q1, q2, rr, wb, g, col, bposw,
                       A1, A2, c1, c2, accA, accB);
        lbp[wid] = bposw;
    }

    // ---- wave reduce across the 16 columns ----
#pragma unroll
    for (int mk = 1; mk <= 8; mk <<= 1) {
#pragma unroll
        for (int r = 0; r < 4; ++r) {
            accA[r] = fmaxf(accA[r], __shfl_xor(accA[r], mk));
            accB[r] = fmaxf(accB[r], __shfl_xor(accB[r], mk));
        }
    }
    if (col == 0) {   // lanes 0,16,32,48 hold dims 4g..4g+3
        *reinterpret_cast<float4*>(&lv[wid][0][4 * g]) =
            make_float4(accA[0], accA[1], accA[2], accA[3]);
        *reinterpret_cast<float4*>(&lv[wid][1][4 * g]) =
            make_float4(accB[0], accB[1], accB[2], accB[3]);
    }
    if (lane == 0) {
        li[wid][0] = idA; li[wid][1] = idB;
        if (!isSlow) lbp[wid] = 0x7fffffff;
    }
    __syncthreads();

    // ---- block combine (<=2 segments per 1024-pt block) ----
    if (threadIdx.x < NH) {
        const int d   = threadIdx.x;
        const int ida = li[0][0];
        const int idb = li[WPB - 1][1];
        float mA = 0.f, mB = 0.f;
#pragma unroll
        for (int s = 0; s < WPB; ++s)
#pragma unroll
            for (int hh = 0; hh < 2; ++hh) {
                const float val = lv[s][hh][d];
                if (li[s][hh] == ida) mA = fmaxf(mA, val);
                else                  mB = fmaxf(mB, val);
            }
        pv[(blockIdx.x * 2 + 0) * NH + d] = mA;
        pv[(blockIdx.x * 2 + 1) * NH + d] = mB;
        if (d == 0) {
            pid[blockIdx.x * 2 + 0] = ida;
            pid[blockIdx.x * 2 + 1] = idb;
            int bp = 0x7fffffff;
#pragma unroll
            for (int s = 0; s < WPB; ++s) {
                if (li[s][0] != ida) bp = min(bp, (int)(blockIdx.x * PPB + s * PTW));
                else if (lbp[s] != 0x7fffffff) bp = min(bp, lbp[s]);
            }
            Rec r; r.idA = ida; r.idB = idb; r.bpos = bp;
            recs[blockIdx.x] = r;
        }
    }
}

// ---------------- stage 2: combine partials, compute gate ----------------
__global__ __launch_bounds__(1024) void stage2_kernel(
    const float* __restrict__ pv, const int* __restrict__ pid,
    const float* __restrict__ Wg, const float* __restrict__ bg,
    const float* __restrict__ gum, float* __restrict__ gate)
{
    __shared__ unsigned int sm[NB * NH];   // 1024 floats-as-bits (vals >= 0)
    const int tid = threadIdx.x;
    sm[tid] = 0u;
    __syncthreads();

    for (int i = tid; i < NENT * 4; i += 1024) {
        const float4 v = reinterpret_cast<const float4*>(pv)[i];
        const int e  = i >> 2;
        const int d0 = (i & 3) * 4;
        const int id = pid[e];
        atomicMax(&sm[id * NH + d0 + 0], __float_as_uint(v.x));
        atomicMax(&sm[id * NH + d0 + 1], __float_as_uint(v.y));
        atomicMax(&sm[id * NH + d0 + 2], __float_as_uint(v.z));
        atomicMax(&sm[id * NH + d0 + 3], __float_as_uint(v.w));
    }
    __syncthreads();

    if (tid < NB) {
        float l0 = bg[0] + gum[tid * 2 + 0];
        float l1 = bg[1] + gum[tid * 2 + 1];
#pragma unroll
        for (int k = 0; k < NH; ++k) {
            const float s = __uint_as_float(sm[tid * NH + k]);
            l0 = fmaf(s, Wg[k * 2 + 0], l0);
            l1 = fmaf(s, Wg[k * 2 + 1], l1);
        }
        gate[tid] = 1.f / (1.f + expf(-(l1 - l0)));   // softmax[:,1], TAU=1
    }
}

// ---------------- B: scale via records (no batch reads) ----------------
__global__ __launch_bounds__(256) void scale_kernel(
    const float* __restrict__ refl,
    const Rec*   __restrict__ recs,
    const float* __restrict__ gate,
    float* __restrict__ out)
{
    const Rec rec = recs[blockIdx.x];          // 1 rec per 1024-pt block
    const float gA = gate[rec.idA];
    const float gB = gate[rec.idB];

    const int p0 = (blockIdx.x * 256 + threadIdx.x) * 4;
    const float4 rr = *reinterpret_cast<const float4*>(refl + p0);
    float4 o;
    o.x = ((p0 + 0) < rec.bpos ? gA : gB) * rr.x;
    o.y = ((p0 + 1) < rec.bpos ? gA : gB) * rr.y;
    o.z = ((p0 + 2) < rec.bpos ? gA : gB) * rr.z;
    o.w = ((p0 + 3) < rec.bpos ? gA : gB) * rr.w;
    *reinterpret_cast<float4*>(out + p0) = o;
}

extern "C" void kernel_launch(void* const* d_in, const int* in_sizes, int n_in,
                              void* d_out, int out_size, void* d_ws, size_t ws_size,
                              hipStream_t stream) {
    const float* pos   = (const float*)d_in[0];
    const float* refl  = (const float*)d_in[1];
    const int*   batch = (const int*)d_in[2];
    const float* gumb  = (const float*)d_in[3];
    const float* W1    = (const float*)d_in[4];
    const float* b1    = (const float*)d_in[5];
    const float* W2    = (const float*)d_in[6];
    const float* b2    = (const float*)d_in[7];
    const float* Wg    = (const float*)d_in[8];
    const float* bg    = (const float*)d_in[9];
    float* out = (float*)d_out;

    // ws layout: pv 512KB | pid 32KB | recs 48KB | gate 256B
    float* pv   = (float*)d_ws;
    int*   pid  = (int*)((char*)d_ws + 524288);
    Rec*   recs = (Rec*)((char*)d_ws + 557056);
    float* gate = (float*)((char*)d_ws + 606208);

    mlp_segmax_kernel<<<NBLK, 256, 0, stream>>>(pos, refl, batch,
                                                W1, b1, W2, b2, pv, pid, recs);
    stage2_kernel<<<1, 1024, 0, stream>>>(pv, pid, Wg, bg, gumb, gate);
    scale_kernel<<<N_PTS / 1024, 256, 0, stream>>>(refl, recs, gate, out);
}

// Round 12
// 50.295 us; speedup vs baseline: 1.2173x; 1.2173x over previous
//
#include <hip/hip_runtime.h>
#include <hip/hip_bf16.h>

// BinaryReflectanceGate: pointwise MLP (4->16->16, relu) -> segment max over
// sorted batch ids [B=64] -> 2-logit gate + gumbel softmax -> scale reflectance.
//
// Round-12: r10 body + bulk load hoist (r11's TLP experiment regressed: more
// waves quadrupled per-wave fixed cost; real constraint is per-wave MLP).
//   - NBLK=2048, SITERS=2 (512 pts/wave), __launch_bounds__(256,4) (<=128 VGPR)
//   - fast path: ALL 8 float4 loads issued at entry, pinned by
//     sched_barrier(0); first use waits vmcnt(4) so chunk-1 loads fly under
//     chunk-0 compute; 4 waves/SIMD x 8 loads = 32 outstanding reqs/SIMD
//   - straight-line phase-split do_chunk (r10, proven): 4x MFMA1 -> 4x pack
//     -> 4x MFMA2, fast/slow split at TOP level
//
// MFMA layout facts (HW-verified r4, absmax 0.0039):
//   C/D: col=lane&15, row=(lane>>4)*4+reg. Lane l owns points 4l..4l+3 of each
//   256-pt chunk (pos floats 12l..12l+11 = 3 aligned float4s + refl float4).
//   In MFMA (j,t), lanes with g==t feed their j-th point; column c's point id
//   = sb + 4*(16t+c) + j (closed form, used for straddle select).

#define N_PTS 4194304
#define NB 64
#define NH 16
#define WPB 4                       // waves per block
#define SITERS 2                    // 256-pt chunks per wave
#define PTW (256 * SITERS)          // 512 points per wave
#define PPB (WPB * PTW)             // 2048 points per block
#define NBLK (N_PTS / PPB)          // 2048 blocks
#define NENT (NBLK * 2)             // 4096 partial entries

typedef __attribute__((ext_vector_type(8))) short bf16x8;
typedef __attribute__((ext_vector_type(4))) float f32x4;
union U8 { bf16x8 v; unsigned u[4]; unsigned short s[8]; };

struct Rec { int idA, idB, bpos; };

__device__ __forceinline__ unsigned pk2(float a, float b) {
    float2 t; t.x = a; t.y = b;
    __hip_bfloat162 r = __float22bfloat162_rn(t);
    unsigned u;
    __builtin_memcpy(&u, &r, sizeof(u));
    return u;
}
__device__ __forceinline__ unsigned short f2bf(float x) {   // RNE, setup only
    unsigned u = __float_as_uint(x);
    u = u + 0x7fffu + ((u >> 16) & 1u);
    return (unsigned short)(u >> 16);
}

// One 256-pt chunk: lane's 4 points through both layers, phase-split for ILP.
template<bool SLOW>
__device__ __forceinline__ void do_chunk(
    const float4& q0, const float4& q1, const float4& q2, const float4& rr,
    int sb, int g, int col, int bposw,
    const U8& A1, const U8& A2, const f32x4& c1, const f32x4& c2,
    f32x4& accA, f32x4& accB)
{
    const float f[4][4] = {{q0.x, q0.y, q0.z, rr.x},
                           {q0.w, q1.x, q1.y, rr.y},
                           {q1.z, q1.w, q2.x, rr.z},
                           {q2.y, q2.z, q2.w, rr.w}};
#pragma unroll
    for (int j = 0; j < 4; ++j) {
        const unsigned F01 = pk2(f[j][0], f[j][1]);
        const unsigned F23 = pk2(f[j][2], f[j][3]);
        f32x4 d[4], h[4];                 // static-indexed (fully unrolled)
#pragma unroll
        for (int t = 0; t < 4; ++t) {     // phase 1: 4 independent MFMA1
            const bool mine = (g == t);
            U8 B;
            B.u[0] = mine ? F01 : 0u;
            B.u[1] = mine ? F23 : 0u;
            B.u[2] = 0u; B.u[3] = 0u;
            d[t] = __builtin_amdgcn_mfma_f32_16x16x32_bf16(A1.v, B.v, c1, 0, 0, 0);
        }
#pragma unroll
        for (int t = 0; t < 4; ++t) {     // phase 2+3: pack, 4 MFMA2
            U8 P;
            P.u[0] = pk2(fmaxf(d[t][0], 0.f), fmaxf(d[t][1], 0.f));
            P.u[1] = pk2(fmaxf(d[t][2], 0.f), fmaxf(d[t][3], 0.f));
            P.u[2] = 0u; P.u[3] = 0u;
            h[t] = __builtin_amdgcn_mfma_f32_16x16x32_bf16(A2.v, P.v, c2, 0, 0, 0);
        }
#pragma unroll
        for (int t = 0; t < 4; ++t) {     // phase 4: accumulate
            if (!SLOW) {
#pragma unroll
                for (int r = 0; r < 4; ++r) accA[r] = fmaxf(accA[r], h[t][r]);
            } else {
                const bool m = (sb + 4 * (16 * t + col) + j) < bposw;
#pragma unroll
                for (int r = 0; r < 4; ++r) {
                    accA[r] = fmaxf(accA[r], m ? h[t][r] : 0.f);
                    accB[r] = fmaxf(accB[r], m ? 0.f : h[t][r]);
                }
            }
        }
    }
}

// ---------------- A: MLP + segment-max partials + records ----------------
__global__ __launch_bounds__(256, 4) void mlp_segmax_kernel(
    const float* __restrict__ pos,    // [N,3]
    const float* __restrict__ refl,   // [N]
    const int*   __restrict__ batch,  // [N] sorted
    const float* __restrict__ W1, const float* __restrict__ b1,
    const float* __restrict__ W2, const float* __restrict__ b2,
    float* __restrict__ pv,           // [NENT,16]
    int*   __restrict__ pid,          // [NENT]
    Rec*   __restrict__ recs)         // [NBLK]
{
    __shared__ float lv[WPB][2][NH];
    __shared__ int   li[WPB][2];
    __shared__ int   lbp[WPB];

    const int lane = threadIdx.x & 63;
    const int wid  = threadIdx.x >> 6;
    const int col  = lane & 15;
    const int g    = lane >> 4;
    const int wb   = (blockIdx.x * WPB + wid) * PTW;

    // weight / bias fragments (L1-cached one-time loads)
    U8 A1, A2;
#pragma unroll
    for (int e = 0; e < 4; ++e) {
        A1.s[e]     = f2bf(W1[e * NH + col]);
        A1.s[e + 4] = 0;
        A2.s[e]     = f2bf(W2[(4 * g + e) * NH + col]);
        A2.s[e + 4] = 0;
    }
    f32x4 c1, c2;
#pragma unroll
    for (int r = 0; r < 4; ++r) { c1[r] = b1[4 * g + r]; c2[r] = b2[4 * g + r]; }

    const int idA = batch[wb];
    const int idB = batch[wb + PTW - 1];
    const bool isSlow = (idA != idB);      // wave-uniform

    f32x4 accA = {0.f, 0.f, 0.f, 0.f};
    f32x4 accB = {0.f, 0.f, 0.f, 0.f};

    const float4* gp = (const float4*)(pos + (size_t)wb * 3);
    const float4* gr = (const float4*)(refl + wb);

    if (!isSlow) {
        // ---- fast path: ALL loads first (pinned), then straight-line MLP ----
        const float4 a0 = gp[3 * lane + 0];
        const float4 a1 = gp[3 * lane + 1];
        const float4 a2 = gp[3 * lane + 2];
        const float4 ar = gr[lane];
        const float4 b0 = gp[192 + 3 * lane + 0];
        const float4 b1v = gp[192 + 3 * lane + 1];
        const float4 b2v = gp[192 + 3 * lane + 2];
        const float4 br = gr[64 + lane];
        __builtin_amdgcn_sched_barrier(0);   // loads may not sink below here
        do_chunk<false>(a0, a1, a2, ar, wb, g, col, 0,
                        A1, A2, c1, c2, accA, accB);
        do_chunk<false>(b0, b1v, b2v, br, wb + 256, g, col, 0,
                        A1, A2, c1, c2, accA, accB);
    } else {
        // ---- slow path (~63 waves): boundary scan, then select-accumulate
        int bposw = 0x7fffffff;
        for (int it = 0; it < PTW / 64; ++it) {
            const int idx = wb + it * 64 + lane;
            const unsigned long long mk = __ballot(batch[idx] != idA);
            if (mk) bposw = min(bposw, wb + it * 64 + (__ffsll((long long)mk) - 1));
        }
#pragma unroll
        for (int s = 0; s < SITERS; ++s) {
            const float4 q0 = gp[s * 192 + 3 * lane + 0];
            const float4 q1 = gp[s * 192 + 3 * lane + 1];
            const float4 q2 = gp[s * 192 + 3 * lane + 2];
            const float4 rr = gr[s * 64 + lane];
            do_chunk<true>(q0, q1, q2, rr, wb + s * 256, g, col, bposw,
                           A1, A2, c1, c2, accA, accB);
        }
        lbp[wid] = bposw;
    }

    // ---- wave reduce across the 16 columns ----
#pragma unroll
    for (int mk = 1; mk <= 8; mk <<= 1) {
#pragma unroll
        for (int r = 0; r < 4; ++r) {
            accA[r] = fmaxf(accA[r], __shfl_xor(accA[r], mk));
            accB[r] = fmaxf(accB[r], __shfl_xor(accB[r], mk));
        }
    }
    if (col == 0) {   // lanes 0,16,32,48 hold dims 4g..4g+3
        *reinterpret_cast<float4*>(&lv[wid][0][4 * g]) =
            make_float4(accA[0], accA[1], accA[2], accA[3]);
        *reinterpret_cast<float4*>(&lv[wid][1][4 * g]) =
            make_float4(accB[0], accB[1], accB[2], accB[3]);
    }
    if (lane == 0) {
        li[wid][0] = idA; li[wid][1] = idB;
        if (!isSlow) lbp[wid] = 0x7fffffff;
    }
    __syncthreads();

    // ---- block combine (<=2 segments per 2048-pt block) ----
    if (threadIdx.x < NH) {
        const int d   = threadIdx.x;
        const int ida = li[0][0];
        const int idb = li[WPB - 1][1];
        float mA = 0.f, mB = 0.f;
#pragma unroll
        for (int s = 0; s < WPB; ++s)
#pragma unroll
            for (int hh = 0; hh < 2; ++hh) {
                const float val = lv[s][hh][d];
                if (li[s][hh] == ida) mA = fmaxf(mA, val);
                else                  mB = fmaxf(mB, val);
            }
        pv[(blockIdx.x * 2 + 0) * NH + d] = mA;
        pv[(blockIdx.x * 2 + 1) * NH + d] = mB;
        if (d == 0) {
            pid[blockIdx.x * 2 + 0] = ida;
            pid[blockIdx.x * 2 + 1] = idb;
            int bp = 0x7fffffff;
#pragma unroll
            for (int s = 0; s < WPB; ++s) {
                if (li[s][0] != ida) bp = min(bp, (int)(blockIdx.x * PPB + s * PTW));
                else if (lbp[s] != 0x7fffffff) bp = min(bp, lbp[s]);
            }
            Rec r; r.idA = ida; r.idB = idb; r.bpos = bp;
            recs[blockIdx.x] = r;
        }
    }
}

// ---------------- stage 2: combine partials, compute gate ----------------
__global__ __launch_bounds__(1024) void stage2_kernel(
    const float* __restrict__ pv, const int* __restrict__ pid,
    const float* __restrict__ Wg, const float* __restrict__ bg,
    const float* __restrict__ gum, float* __restrict__ gate)
{
    __shared__ unsigned int sm[NB * NH];   // 1024 floats-as-bits (vals >= 0)
    const int tid = threadIdx.x;
    sm[tid] = 0u;
    __syncthreads();

    for (int i = tid; i < NENT * 4; i += 1024) {
        const float4 v = reinterpret_cast<const float4*>(pv)[i];
        const int e  = i >> 2;
        const int d0 = (i & 3) * 4;
        const int id = pid[e];
        atomicMax(&sm[id * NH + d0 + 0], __float_as_uint(v.x));
        atomicMax(&sm[id * NH + d0 + 1], __float_as_uint(v.y));
        atomicMax(&sm[id * NH + d0 + 2], __float_as_uint(v.z));
        atomicMax(&sm[id * NH + d0 + 3], __float_as_uint(v.w));
    }
    __syncthreads();

    if (tid < NB) {
        float l0 = bg[0] + gum[tid * 2 + 0];
        float l1 = bg[1] + gum[tid * 2 + 1];
#pragma unroll
        for (int k = 0; k < NH; ++k) {
            const float s = __uint_as_float(sm[tid * NH + k]);
            l0 = fmaf(s, Wg[k * 2 + 0], l0);
            l1 = fmaf(s, Wg[k * 2 + 1], l1);
        }
        gate[tid] = 1.f / (1.f + expf(-(l1 - l0)));   // softmax[:,1], TAU=1
    }
}

// ---------------- B: scale via records (no batch reads) ----------------
__global__ __launch_bounds__(256) void scale_kernel(
    const float* __restrict__ refl,
    const Rec*   __restrict__ recs,
    const float* __restrict__ gate,
    float* __restrict__ out)
{
    const Rec rec = recs[blockIdx.x >> 1];     // 2 scale-blocks per A-block
    const float gA = gate[rec.idA];
    const float gB = gate[rec.idB];

    const int p0 = (blockIdx.x * 256 + threadIdx.x) * 4;
    const float4 rr = *reinterpret_cast<const float4*>(refl + p0);
    float4 o;
    o.x = ((p0 + 0) < rec.bpos ? gA : gB) * rr.x;
    o.y = ((p0 + 1) < rec.bpos ? gA : gB) * rr.y;
    o.z = ((p0 + 2) < rec.bpos ? gA : gB) * rr.z;
    o.w = ((p0 + 3) < rec.bpos ? gA : gB) * rr.w;
    *reinterpret_cast<float4*>(out + p0) = o;
}

extern "C" void kernel_launch(void* const* d_in, const int* in_sizes, int n_in,
                              void* d_out, int out_size, void* d_ws, size_t ws_size,
                              hipStream_t stream) {
    const float* pos   = (const float*)d_in[0];
    const float* refl  = (const float*)d_in[1];
    const int*   batch = (const int*)d_in[2];
    const float* gumb  = (const float*)d_in[3];
    const float* W1    = (const float*)d_in[4];
    const float* b1    = (const float*)d_in[5];
    const float* W2    = (const float*)d_in[6];
    const float* b2    = (const float*)d_in[7];
    const float* Wg    = (const float*)d_in[8];
    const float* bg    = (const float*)d_in[9];
    float* out = (float*)d_out;

    // ws layout: pv 256KB | pid 16KB | recs 24KB | gate 256B
    float* pv   = (float*)d_ws;
    int*   pid  = (int*)((char*)d_ws + 262144);
    Rec*   recs = (Rec*)((char*)d_ws + 278528);
    float* gate = (float*)((char*)d_ws + 303104);

    mlp_segmax_kernel<<<NBLK, 256, 0, stream>>>(pos, refl, batch,
                                                W1, b1, W2, b2, pv, pid, recs);
    stage2_kernel<<<1, 1024, 0, stream>>>(pv, pid, Wg, bg, gumb, gate);
    scale_kernel<<<N_PTS / 1024, 256, 0, stream>>>(refl, recs, gate, out);
}

// Round 13
// 42.019 us; speedup vs baseline: 1.4571x; 1.1970x over previous
//
#include <hip/hip_runtime.h>
#include <hip/hip_bf16.h>

// BinaryReflectanceGate: pointwise MLP (4->16->16, relu) -> segment max over
// sorted batch ids [B=64] -> 2-logit gate + gumbel softmax -> scale reflectance.
//
// Round-13: r12 body + INLINE-ASM staged loads with counted vmcnt (T4).
//   hipcc provably sinks/serializes source-level prefetch (r9/r10/r12 all
//   landed at VGPR<=52). asm volatile global_load_dwordx4 into named regs
//   cannot be sunk; counted s_waitcnt vmcnt(N) + sched_barrier(0) (rule #18)
//   retire exactly one stage while the next stays in flight.
//   Schedule (4 stages, 2-reg-buffer ring, copies break WAR before reissue):
//     issue s0,s1 | s: wait vmcnt(4) -> copy -> issue s+2 -> compute
//
// MFMA layout facts (HW-verified r4, absmax 0.0039):
//   C/D: col=lane&15, row=(lane>>4)*4+reg. Lane l owns points 4l..4l+3 of each
//   256-pt chunk (pos floats 12l..12l+11 = 3 aligned float4s + refl float4).
//   In MFMA (j,t), lanes with g==t feed their j-th point; column c's point id
//   = sb + 4*(16t+c) + j (closed form, used for straddle select).

#define N_PTS 4194304
#define NB 64
#define NH 16
#define WPB 4                       // waves per block
#define SITERS 4                    // 256-pt chunks per wave
#define PTW (256 * SITERS)          // 1024 points per wave
#define PPB (WPB * PTW)             // 4096 points per block
#define NBLK (N_PTS / PPB)          // 1024 blocks
#define NENT (NBLK * 2)             // 2048 partial entries

typedef __attribute__((ext_vector_type(8))) short bf16x8;
typedef __attribute__((ext_vector_type(4))) float f32x4;
union U8 { bf16x8 v; unsigned u[4]; unsigned short s[8]; };

struct Rec { int idA, idB, bpos; };

__device__ __forceinline__ unsigned pk2(float a, float b) {
    float2 t; t.x = a; t.y = b;
    __hip_bfloat162 r = __float22bfloat162_rn(t);
    unsigned u;
    __builtin_memcpy(&u, &r, sizeof(u));
    return u;
}
__device__ __forceinline__ unsigned short f2bf(float x) {   // RNE, setup only
    unsigned u = __float_as_uint(x);
    u = u + 0x7fffu + ((u >> 16) & 1u);
    return (unsigned short)(u >> 16);
}

// volatile asm load: cannot be sunk or eliminated by the scheduler
#define GLOAD(dst, addr) \
    asm volatile("global_load_dwordx4 %0, %1, off" : "=v"(dst) : "v"(addr))
// counted wait + mandatory scheduling fence (rule #18)
#define VWAIT(n) do { \
    asm volatile("s_waitcnt vmcnt(" #n ")" ::: "memory"); \
    __builtin_amdgcn_sched_barrier(0); } while (0)

// One 256-pt chunk: lane's 4 points through both layers, phase-split for ILP.
template<bool SLOW>
__device__ __forceinline__ void do_chunk(
    const f32x4& q0, const f32x4& q1, const f32x4& q2, const f32x4& rr,
    int sb, int g, int col, int bposw,
    const U8& A1, const U8& A2, const f32x4& c1, const f32x4& c2,
    f32x4& accA, f32x4& accB)
{
    const float f[4][4] = {{q0[0], q0[1], q0[2], rr[0]},
                           {q0[3], q1[0], q1[1], rr[1]},
                           {q1[2], q1[3], q2[0], rr[2]},
                           {q2[1], q2[2], q2[3], rr[3]}};
#pragma unroll
    for (int j = 0; j < 4; ++j) {
        const unsigned F01 = pk2(f[j][0], f[j][1]);
        const unsigned F23 = pk2(f[j][2], f[j][3]);
        f32x4 d[4], h[4];                 // static-indexed (fully unrolled)
#pragma unroll
        for (int t = 0; t < 4; ++t) {     // phase 1: 4 independent MFMA1
            const bool mine = (g == t);
            U8 B;
            B.u[0] = mine ? F01 : 0u;
            B.u[1] = mine ? F23 : 0u;
            B.u[2] = 0u; B.u[3] = 0u;
            d[t] = __builtin_amdgcn_mfma_f32_16x16x32_bf16(A1.v, B.v, c1, 0, 0, 0);
        }
#pragma unroll
        for (int t = 0; t < 4; ++t) {     // phase 2+3: pack, 4 MFMA2
            U8 P;
            P.u[0] = pk2(fmaxf(d[t][0], 0.f), fmaxf(d[t][1], 0.f));
            P.u[1] = pk2(fmaxf(d[t][2], 0.f), fmaxf(d[t][3], 0.f));
            P.u[2] = 0u; P.u[3] = 0u;
            h[t] = __builtin_amdgcn_mfma_f32_16x16x32_bf16(A2.v, P.v, c2, 0, 0, 0);
        }
#pragma unroll
        for (int t = 0; t < 4; ++t) {     // phase 4: accumulate
            if (!SLOW) {
#pragma unroll
                for (int r = 0; r < 4; ++r) accA[r] = fmaxf(accA[r], h[t][r]);
            } else {
                const bool m = (sb + 4 * (16 * t + col) + j) < bposw;
#pragma unroll
                for (int r = 0; r < 4; ++r) {
                    accA[r] = fmaxf(accA[r], m ? h[t][r] : 0.f);
                    accB[r] = fmaxf(accB[r], m ? 0.f : h[t][r]);
                }
            }
        }
    }
}

// ---------------- A: MLP + segment-max partials + records ----------------
__global__ __launch_bounds__(256, 4) void mlp_segmax_kernel(
    const float* __restrict__ pos,    // [N,3]
    const float* __restrict__ refl,   // [N]
    const int*   __restrict__ batch,  // [N] sorted
    const float* __restrict__ W1, const float* __restrict__ b1,
    const float* __restrict__ W2, const float* __restrict__ b2,
    float* __restrict__ pv,           // [NENT,16]
    int*   __restrict__ pid,          // [NENT]
    Rec*   __restrict__ recs)         // [NBLK]
{
    __shared__ float lv[WPB][2][NH];
    __shared__ int   li[WPB][2];
    __shared__ int   lbp[WPB];

    const int lane = threadIdx.x & 63;
    const int wid  = threadIdx.x >> 6;
    const int col  = lane & 15;
    const int g    = lane >> 4;
    const int wb   = (blockIdx.x * WPB + wid) * PTW;

    // weight / bias fragments (L1-cached one-time loads)
    U8 A1, A2;
#pragma unroll
    for (int e = 0; e < 4; ++e) {
        A1.s[e]     = f2bf(W1[e * NH + col]);
        A1.s[e + 4] = 0;
        A2.s[e]     = f2bf(W2[(4 * g + e) * NH + col]);
        A2.s[e + 4] = 0;
    }
    f32x4 c1, c2;
#pragma unroll
    for (int r = 0; r < 4; ++r) { c1[r] = b1[4 * g + r]; c2[r] = b2[4 * g + r]; }

    const int idA = batch[wb];
    const int idB = batch[wb + PTW - 1];
    const bool isSlow = (idA != idB);      // wave-uniform

    f32x4 accA = {0.f, 0.f, 0.f, 0.f};
    f32x4 accB = {0.f, 0.f, 0.f, 0.f};

    const f32x4* gp = (const f32x4*)(pos + (size_t)wb * 3);
    const f32x4* gr = (const f32x4*)(refl + wb);

    if (!isSlow) {
        // ---- fast path: asm-staged ring, counted vmcnt ----
        f32x4 s0a, s0b, s0c, s0r;          // buffer 0 (stages 0,2)
        f32x4 s1a, s1b, s1c, s1r;          // buffer 1 (stages 1,3)

        GLOAD(s0a, gp + 0 * 192 + 3 * lane + 0);
        GLOAD(s0b, gp + 0 * 192 + 3 * lane + 1);
        GLOAD(s0c, gp + 0 * 192 + 3 * lane + 2);
        GLOAD(s0r, gr + 0 * 64 + lane);
        GLOAD(s1a, gp + 1 * 192 + 3 * lane + 0);
        GLOAD(s1b, gp + 1 * 192 + 3 * lane + 1);
        GLOAD(s1c, gp + 1 * 192 + 3 * lane + 2);
        GLOAD(s1r, gr + 1 * 64 + lane);

        // ---- s=0: stage0 done (4 newer in flight), reissue buf0 -> stage2
        VWAIT(4);
        { f32x4 q0 = s0a, q1 = s0b, q2 = s0c, rr = s0r;   // WAR: copy before reissue
          GLOAD(s0a, gp + 2 * 192 + 3 * lane + 0);
          GLOAD(s0b, gp + 2 * 192 + 3 * lane + 1);
          GLOAD(s0c, gp + 2 * 192 + 3 * lane + 2);
          GLOAD(s0r, gr + 2 * 64 + lane);
          do_chunk<false>(q0, q1, q2, rr, wb + 0 * 256, g, col, 0,
                          A1, A2, c1, c2, accA, accB); }

        // ---- s=1: stage1 done, reissue buf1 -> stage3
        VWAIT(4);
        { f32x4 q0 = s1a, q1 = s1b, q2 = s1c, rr = s1r;
          GLOAD(s1a, gp + 3 * 192 + 3 * lane + 0);
          GLOAD(s1b, gp + 3 * 192 + 3 * lane + 1);
          GLOAD(s1c, gp + 3 * 192 + 3 * lane + 2);
          GLOAD(s1r, gr + 3 * 64 + lane);
          do_chunk<false>(q0, q1, q2, rr, wb + 1 * 256, g, col, 0,
                          A1, A2, c1, c2, accA, accB); }

        // ---- s=2: stage2 done (stage3 still in flight)
        VWAIT(4);
        do_chunk<false>(s0a, s0b, s0c, s0r, wb + 2 * 256, g, col, 0,
                        A1, A2, c1, c2, accA, accB);

        // ---- s=3: drain
        VWAIT(0);
        do_chunk<false>(s1a, s1b, s1c, s1r, wb + 3 * 256, g, col, 0,
                        A1, A2, c1, c2, accA, accB);
    } else {
        // ---- slow path (~63 waves): boundary scan, then select-accumulate
        int bposw = 0x7fffffff;
        for (int it = 0; it < PTW / 64; ++it) {
            const int idx = wb + it * 64 + lane;
            const unsigned long long mk = __ballot(batch[idx] != idA);
            if (mk) bposw = min(bposw, wb + it * 64 + (__ffsll((long long)mk) - 1));
        }
#pragma unroll
        for (int s = 0; s < SITERS; ++s) {
            const f32x4 q0 = gp[s * 192 + 3 * lane + 0];
            const f32x4 q1 = gp[s * 192 + 3 * lane + 1];
            const f32x4 q2 = gp[s * 192 + 3 * lane + 2];
            const f32x4 rr = gr[s * 64 + lane];
            do_chunk<true>(q0, q1, q2, rr, wb + s * 256, g, col, bposw,
                           A1, A2, c1, c2, accA, accB);
        }
        lbp[wid] = bposw;
    }

    // ---- wave reduce across the 16 columns ----
#pragma unroll
    for (int mk = 1; mk <= 8; mk <<= 1) {
#pragma unroll
        for (int r = 0; r < 4; ++r) {
            accA[r] = fmaxf(accA[r], __shfl_xor(accA[r], mk));
            accB[r] = fmaxf(accB[r], __shfl_xor(accB[r], mk));
        }
    }
    if (col == 0) {   // lanes 0,16,32,48 hold dims 4g..4g+3
        *reinterpret_cast<float4*>(&lv[wid][0][4 * g]) =
            make_float4(accA[0], accA[1], accA[2], accA[3]);
        *reinterpret_cast<float4*>(&lv[wid][1][4 * g]) =
            make_float4(accB[0], accB[1], accB[2], accB[3]);
    }
    if (lane == 0) {
        li[wid][0] = idA; li[wid][1] = idB;
        if (!isSlow) lbp[wid] = 0x7fffffff;
    }
    __syncthreads();

    // ---- block combine (<=2 segments per 4096-pt block) ----
    if (threadIdx.x < NH) {
        const int d   = threadIdx.x;
        const int ida = li[0][0];
        const int idb = li[WPB - 1][1];
        float mA = 0.f, mB = 0.f;
#pragma unroll
        for (int s = 0; s < WPB; ++s)
#pragma unroll
            for (int hh = 0; hh < 2; ++hh) {
                const float val = lv[s][hh][d];
                if (li[s][hh] == ida) mA = fmaxf(mA, val);
                else                  mB = fmaxf(mB, val);
            }
        pv[(blockIdx.x * 2 + 0) * NH + d] = mA;
        pv[(blockIdx.x * 2 + 1) * NH + d] = mB;
        if (d == 0) {
            pid[blockIdx.x * 2 + 0] = ida;
            pid[blockIdx.x * 2 + 1] = idb;
            int bp = 0x7fffffff;
#pragma unroll
            for (int s = 0; s < WPB; ++s) {
                if (li[s][0] != ida) bp = min(bp, (int)(blockIdx.x * PPB + s * PTW));
                else if (lbp[s] != 0x7fffffff) bp = min(bp, lbp[s]);
            }
            Rec r; r.idA = ida; r.idB = idb; r.bpos = bp;
            recs[blockIdx.x] = r;
        }
    }
}

// ---------------- stage 2: combine partials, compute gate ----------------
__global__ __launch_bounds__(1024) void stage2_kernel(
    const float* __restrict__ pv, const int* __restrict__ pid,
    const float* __restrict__ Wg, const float* __restrict__ bg,
    const float* __restrict__ gum, float* __restrict__ gate)
{
    __shared__ unsigned int sm[NB * NH];   // 1024 floats-as-bits (vals >= 0)
    const int tid = threadIdx.x;
    sm[tid] = 0u;
    __syncthreads();

    for (int i = tid; i < NENT * 4; i += 1024) {
        const float4 v = reinterpret_cast<const float4*>(pv)[i];
        const int e  = i >> 2;
        const int d0 = (i & 3) * 4;
        const int id = pid[e];
        atomicMax(&sm[id * NH + d0 + 0], __float_as_uint(v.x));
        atomicMax(&sm[id * NH + d0 + 1], __float_as_uint(v.y));
        atomicMax(&sm[id * NH + d0 + 2], __float_as_uint(v.z));
        atomicMax(&sm[id * NH + d0 + 3], __float_as_uint(v.w));
    }
    __syncthreads();

    if (tid < NB) {
        float l0 = bg[0] + gum[tid * 2 + 0];
        float l1 = bg[1] + gum[tid * 2 + 1];
#pragma unroll
        for (int k = 0; k < NH; ++k) {
            const float s = __uint_as_float(sm[tid * NH + k]);
            l0 = fmaf(s, Wg[k * 2 + 0], l0);
            l1 = fmaf(s, Wg[k * 2 + 1], l1);
        }
        gate[tid] = 1.f / (1.f + expf(-(l1 - l0)));   // softmax[:,1], TAU=1
    }
}

// ---------------- B: scale via records (no batch reads) ----------------
__global__ __launch_bounds__(256) void scale_kernel(
    const float* __restrict__ refl,
    const Rec*   __restrict__ recs,
    const float* __restrict__ gate,
    float* __restrict__ out)
{
    const Rec rec = recs[blockIdx.x >> 2];     // 4 scale-blocks per A-block
    const float gA = gate[rec.idA];
    const float gB = gate[rec.idB];

    const int p0 = (blockIdx.x * 256 + threadIdx.x) * 4;
    const float4 rr = *reinterpret_cast<const float4*>(refl + p0);
    float4 o;
    o.x = ((p0 + 0) < rec.bpos ? gA : gB) * rr.x;
    o.y = ((p0 + 1) < rec.bpos ? gA : gB) * rr.y;
    o.z = ((p0 + 2) < rec.bpos ? gA : gB) * rr.z;
    o.w = ((p0 + 3) < rec.bpos ? gA : gB) * rr.w;
    *reinterpret_cast<float4*>(out + p0) = o;
}

extern "C" void kernel_launch(void* const* d_in, const int* in_sizes, int n_in,
                              void* d_out, int out_size, void* d_ws, size_t ws_size,
                              hipStream_t stream) {
    const float* pos   = (const float*)d_in[0];
    const float* refl  = (const float*)d_in[1];
    const int*   batch = (const int*)d_in[2];
    const float* gumb  = (const float*)d_in[3];
    const float* W1    = (const float*)d_in[4];
    const float* b1    = (const float*)d_in[5];
    const float* W2    = (const float*)d_in[6];
    const float* b2    = (const float*)d_in[7];
    const float* Wg    = (const float*)d_in[8];
    const float* bg    = (const float*)d_in[9];
    float* out = (float*)d_out;

    // ws layout: pv 128KB | pid 8KB | recs 12KB | gate 256B
    float* pv   = (float*)d_ws;
    int*   pid  = (int*)((char*)d_ws + 131072);
    Rec*   recs = (Rec*)((char*)d_ws + 139264);
    float* gate = (float*)((char*)d_ws + 151552);

    mlp_segmax_kernel<<<NBLK, 256, 0, stream>>>(pos, refl, batch,
                                                W1, b1, W2, b2, pv, pid, recs);
    stage2_kernel<<<1, 1024, 0, stream>>>(pv, pid, Wg, bg, gumb, gate);
    scale_kernel<<<N_PTS / 1024, 256, 0, stream>>>(refl, recs, gate, out);
}